// Round 4
// baseline (433.213 us; speedup 1.0000x reference)
//
#include <hip/hip_runtime.h>

#define IMG_W 2048
#define IMG_H 2048
#define OUT_W 2044
#define OUT_H 2044
#define OUT_HW (2044 * 2044)

// Per-WG: TI output rows x NTILE successive j-tiles of TJ cols, 14 d-planes.
#define TI 16
#define TJ 64
#define NTILE 4
#define LR (TI + 4)   // staged input rows per tile
#define LC (TJ + 4)   // staged input cols per tile
#define LSTR 69       // LDS row stride in 16B pixel-records

typedef int v4i __attribute__((ext_vector_type(4)));

// Build MFMA A-fragments from weights (unchanged — verified bit-exact, absmax 0.125).
// GEMM: D[m][n] = sum_k A[m][k]*B[k][n]; m = channel d, k = (pair p, bit-plane c),
// p = 4t + (lane>>4) over 7 chunks (25 real (kh,kw) pairs + 3 zero pads).
// Nibble split keeps operands signed-i8-safe; recombine 16*hi + lo exactly.
__global__ void quant_frag(const float* __restrict__ w, v4i* __restrict__ wfrag) {
    const int l = threadIdx.x;
    const int m = l & 15, g = l >> 4;
    #pragma unroll
    for (int t = 0; t < 7; ++t) {
        const int p = 4 * t + g;
        unsigned lo[4] = {0, 0, 0, 0}, hi[4] = {0, 0, 0, 0};
        if (p < 25 && m < 14) {
            const int kh = p / 5, kw = p % 5;
            #pragma unroll
            for (int kd = 0; kd < 3; ++kd) {
                const int e = m + kd;
                const unsigned w8 = (unsigned)(int)rintf(w[(kd * 5 + kh) * 5 + kw] * 255.0f);
                lo[e >> 2] |= (w8 & 15u) << (8 * (e & 3));
                hi[e >> 2] |= (w8 >> 4)  << (8 * (e & 3));
            }
        }
        v4i vlo, vhi;
        vlo.x = (int)lo[0]; vlo.y = (int)lo[1]; vlo.z = (int)lo[2]; vlo.w = (int)lo[3];
        vhi.x = (int)hi[0]; vhi.y = (int)hi[1]; vhi.z = (int)hi[2]; vhi.w = (int)hi[3];
        wfrag[t * 64 + l]       = vlo;
        wfrag[448 + t * 64 + l] = vhi;
    }
}

// Pixel-major bit-expansion in LDS (16 B/pixel = 16 bit-planes); one ds_read_b128
// per lane per k-chunk is a full B-fragment for mfma_i32_16x16x64_i8.
// (1) nontemporal stores (no L2 write-allocate RMW on the poison-evicted output),
// (2) 4 j-tiles per WG with register prefetch of the next tile's raw pixels so
// global-load latency hides under compute.
__global__ __launch_bounds__(256, 3) void conv_mfma(
        const int* __restrict__ x, const v4i* __restrict__ wfrag,
        const float* __restrict__ bias, float* __restrict__ out) {
    __shared__ v4i vt[LR * LSTR];
    const int tid  = threadIdx.x;
    const int lane = tid & 63;
    const int wv   = tid >> 6;     // wave 0..3
    const int m16  = lane & 15;    // pixel-in-group (B) / channel row (A)
    const int g4   = lane >> 4;    // k-subgroup / D row-block
    const int I0 = blockIdx.y * TI;
    const int J0 = blockIdx.x * (TJ * NTILE);

    // A-fragments: global loads issue first, overlap the first staging phase.
    v4i alo[7], ahi[7];
    #pragma unroll
    for (int t = 0; t < 7; ++t) {
        alo[t] = wfrag[t * 64 + lane];
        ahi[t] = wfrag[448 + t * 64 + lane];
    }
    const float b0 = bias[0];

    // Per-lane k-chunk record offsets (pads -> (0,0), weights are zero there).
    int koff[7];
    #pragma unroll
    for (int t = 0; t < 7; ++t) {
        const int p  = 4 * t + g4;
        const int kh = (p < 25) ? (p / 5) : 0;
        const int kw = (p < 25) ? (p - kh * 5) : 0;
        koff[t] = kh * LSTR + kw;
    }

    const float scale = 1.0f / 255.0f;

    // Raw staged pixels for one tile: rows r = wv + 4*rr (rr<5), cols lane + 64*cc.
    unsigned raw[10];

    auto PREFETCH = [&](int tj) {
        const int Jb = J0 + tj * TJ;
        #pragma unroll
        for (int rr = 0; rr < 5; ++rr) {
            const int gr = min(I0 + wv + rr * 4, IMG_H - 1);
            const long rowoff = (long)gr * IMG_W;
            #pragma unroll
            for (int cc = 0; cc < 2; ++cc) {
                const int col = lane + cc * 64;
                if (col < LC) {
                    const int gc = min(Jb + col, IMG_W - 1);
                    raw[rr * 2 + cc] = (unsigned)x[rowoff + gc];
                }
            }
        }
    };

    auto EXPAND = [&]() {
        #pragma unroll
        for (int rr = 0; rr < 5; ++rr) {
            const int r = wv + rr * 4;
            #pragma unroll
            for (int cc = 0; cc < 2; ++cc) {
                const int col = lane + cc * 64;
                if (col < LC) {
                    const unsigned v = raw[rr * 2 + cc];
                    v4i e;  // byte c of record = bit c of pixel
                    e.x = (int)(__umul24( v         & 0xFu, 0x00204081u) & 0x01010101u);
                    e.y = (int)(__umul24((v >> 4)   & 0xFu, 0x00204081u) & 0x01010101u);
                    e.z = (int)(__umul24((v >> 8)   & 0xFu, 0x00204081u) & 0x01010101u);
                    e.w = (int)(__umul24((v >> 12)  & 0xFu, 0x00204081u) & 0x01010101u);
                    vt[r * LSTR + col] = e;
                }
            }
        }
    };

    PREFETCH(0);

    #pragma unroll 1
    for (int tj = 0; tj < NTILE; ++tj) {
        EXPAND();
        __syncthreads();                      // vt ready for this tile
        if (tj + 1 < NTILE) PREFETCH(tj + 1); // next tile's HBM latency hides here

        const int Jb = J0 + tj * TJ;
        #pragma unroll 2
        for (int it = 0; it < 16; ++it) {
            const int il  = wv * 4 + (it >> 2);
            const int rec = il * LSTR + (it & 3) * 16 + m16;
            v4i bf[7];
            #pragma unroll
            for (int t = 0; t < 7; ++t) bf[t] = vt[rec + koff[t]];

            v4i al0 = {0,0,0,0}, al1 = {0,0,0,0}, ah0 = {0,0,0,0}, ah1 = {0,0,0,0};
            #pragma unroll
            for (int t = 0; t < 6; t += 2) {   // 4 interleaved chains for MFMA ILP
                al0 = __builtin_amdgcn_mfma_i32_16x16x64_i8(alo[t],     bf[t],     al0, 0, 0, 0);
                ah0 = __builtin_amdgcn_mfma_i32_16x16x64_i8(ahi[t],     bf[t],     ah0, 0, 0, 0);
                al1 = __builtin_amdgcn_mfma_i32_16x16x64_i8(alo[t + 1], bf[t + 1], al1, 0, 0, 0);
                ah1 = __builtin_amdgcn_mfma_i32_16x16x64_i8(ahi[t + 1], bf[t + 1], ah1, 0, 0, 0);
            }
            al0 = __builtin_amdgcn_mfma_i32_16x16x64_i8(alo[6], bf[6], al0, 0, 0, 0);
            ah0 = __builtin_amdgcn_mfma_i32_16x16x64_i8(ahi[6], bf[6], ah0, 0, 0, 0);

            // D layout: col = lane&15 = pixel j, row = g4*4 + r = channel d
            const int i = I0 + il;
            const int j = Jb + (it & 3) * 16 + m16;
            if (i < OUT_H && j < OUT_W) {
                float* o = out + (size_t)(g4 * 4) * OUT_HW + (size_t)i * OUT_W + j;
                #pragma unroll
                for (int r = 0; r < 4; ++r) {
                    if (r < 2 || g4 < 3) {     // d = g4*4 + r < 14
                        const int acc = (ah0[r] + ah1[r]) * 16 + (al0[r] + al1[r]);
                        __builtin_nontemporal_store(fmaf((float)acc, scale, b0),
                                                    o + (size_t)r * OUT_HW);
                    }
                }
            }
        }
        __syncthreads();                      // all reads of vt done before overwrite
    }
}

extern "C" void kernel_launch(void* const* d_in, const int* in_sizes, int n_in,
                              void* d_out, int out_size, void* d_ws, size_t ws_size,
                              hipStream_t stream) {
    const int* x      = (const int*)d_in[0];
    const float* w    = (const float*)d_in[1];
    const float* bias = (const float*)d_in[2];
    float* out        = (float*)d_out;
    v4i* wfrag        = (v4i*)d_ws;   // 896 * 16B = 14336 B of workspace

    quant_frag<<<1, 64, 0, stream>>>(w, wfrag);
    conv_mfma<<<dim3((OUT_W + TJ * NTILE - 1) / (TJ * NTILE), (OUT_H + TI - 1) / TI), 256, 0,
                stream>>>(x, wfrag, bias, out);
}

// Round 5
// 293.258 us; speedup vs baseline: 1.4772x; 1.4772x over previous
//
#include <hip/hip_runtime.h>

#define IMG_W 2048
#define IMG_H 2048
#define OUT_W 2044
#define OUT_H 2044
#define OUT_HW (2044 * 2044)

// Workgroup output tile: TI rows x TJ cols, 14 d-planes deep.
#define TI 16
#define TJ 64
#define LR (TI + 4)   // staged input rows
#define LC (TJ + 4)   // staged input cols
#define LSTR 69       // LDS row stride in 16B pixel-records
#define TRP 17        // transpose-buffer inner stride (odd -> conflict-free)

typedef int v4i __attribute__((ext_vector_type(4)));
typedef float v4f __attribute__((ext_vector_type(4)));

// Build MFMA A-fragments from weights (unchanged — verified bit-exact, absmax 0.125).
// GEMM: D[m][n] = sum_k A[m][k]*B[k][n]; m = channel d, k = (pair p, bit-plane c),
// p = 4t + (lane>>4) over 7 chunks (25 real (kh,kw) pairs + 3 zero pads).
// Nibble split keeps operands signed-i8-safe; recombine 16*hi + lo exactly.
__global__ void quant_frag(const float* __restrict__ w, v4i* __restrict__ wfrag) {
    const int l = threadIdx.x;
    const int m = l & 15, g = l >> 4;
    #pragma unroll
    for (int t = 0; t < 7; ++t) {
        const int p = 4 * t + g;
        unsigned lo[4] = {0, 0, 0, 0}, hi[4] = {0, 0, 0, 0};
        if (p < 25 && m < 14) {
            const int kh = p / 5, kw = p % 5;
            #pragma unroll
            for (int kd = 0; kd < 3; ++kd) {
                const int e = m + kd;
                const unsigned w8 = (unsigned)(int)rintf(w[(kd * 5 + kh) * 5 + kw] * 255.0f);
                lo[e >> 2] |= (w8 & 15u) << (8 * (e & 3));
                hi[e >> 2] |= (w8 >> 4)  << (8 * (e & 3));
            }
        }
        v4i vlo, vhi;
        vlo.x = (int)lo[0]; vlo.y = (int)lo[1]; vlo.z = (int)lo[2]; vlo.w = (int)lo[3];
        vhi.x = (int)hi[0]; vhi.y = (int)hi[1]; vhi.z = (int)hi[2]; vhi.w = (int)hi[3];
        wfrag[t * 64 + l]       = vlo;
        wfrag[448 + t * 64 + l] = vhi;
    }
}

// Pixel-major bit-expansion in LDS (16 B/pixel = 16 bit-planes); one ds_read_b128
// per lane per k-chunk is a full B-fragment for mfma_i32_16x16x64_i8.
// Epilogue: per-wave LDS transpose so every global store is a fully-contiguous
// 256-B line (out[d][i][J0..J0+63], lane = j). Regular cached stores (L2 merge).
__global__ __launch_bounds__(256, 2) void conv_mfma(
        const int* __restrict__ x, const v4i* __restrict__ wfrag,
        const float* __restrict__ bias, float* __restrict__ out) {
    __shared__ v4i vt[LR * LSTR];            // 22.1 KB
    __shared__ float trp[4 * 64 * TRP];      // 17.4 KB (per-wave 64x17 floats)
    const int tid  = threadIdx.x;
    const int lane = tid & 63;
    const int wv   = tid >> 6;     // wave 0..3
    const int m16  = lane & 15;    // pixel-in-group (B) / channel row (A)
    const int g4   = lane >> 4;    // k-subgroup / D row-block
    const int I0 = blockIdx.y * TI;
    const int J0 = blockIdx.x * TJ;

    // A-fragments: issued first so the loads overlap the staging phase below.
    v4i alo[7], ahi[7];
    #pragma unroll
    for (int t = 0; t < 7; ++t) {
        alo[t] = wfrag[t * 64 + lane];
        ahi[t] = wfrag[448 + t * 64 + lane];
    }
    const float b0 = bias[0];

    // ---- stage + bit-expand LR x LC pixels (direct load -> expand -> ds_write) ----
    #pragma unroll
    for (int rr = 0; rr < 5; ++rr) {
        const int r  = wv + rr * 4;                        // 0..19
        const int gr = min(I0 + r, IMG_H - 1);
        const long rowoff = (long)gr * IMG_W;
        #pragma unroll
        for (int cc = 0; cc < 2; ++cc) {
            const int col = lane + cc * 64;
            if (col < LC) {
                const int gc = min(J0 + col, IMG_W - 1);
                const unsigned v = (unsigned)x[rowoff + gc];
                v4i e;  // byte c of record = bit c of pixel
                e.x = (int)(__umul24( v         & 0xFu, 0x00204081u) & 0x01010101u);
                e.y = (int)(__umul24((v >> 4)   & 0xFu, 0x00204081u) & 0x01010101u);
                e.z = (int)(__umul24((v >> 8)   & 0xFu, 0x00204081u) & 0x01010101u);
                e.w = (int)(__umul24((v >> 12)  & 0xFu, 0x00204081u) & 0x01010101u);
                vt[r * LSTR + col] = e;
            }
        }
    }
    __syncthreads();

    // Per-lane k-chunk record offsets (pads -> (0,0), weights are zero there).
    int koff[7];
    #pragma unroll
    for (int t = 0; t < 7; ++t) {
        const int p  = 4 * t + g4;
        const int kh = (p < 25) ? (p / 5) : 0;
        const int kw = (p < 25) ? (p - kh * 5) : 0;
        koff[t] = kh * LSTR + kw;
    }

    const float scale = 1.0f / 255.0f;
    float* twr = trp + wv * (64 * TRP);      // this wave's private transpose buffer

    // ---- per output row (wave wv owns rows 4wv .. 4wv+3) ----
    #pragma unroll 1
    for (int il_ = 0; il_ < 4; ++il_) {
        const int il = wv * 4 + il_;

        // 4 column-groups of 16 pixels: compute and stage into trp
        #pragma unroll
        for (int jg = 0; jg < 4; ++jg) {
            const int rec = il * LSTR + jg * 16 + m16;
            v4i bf[7];
            #pragma unroll
            for (int t = 0; t < 7; ++t) bf[t] = vt[rec + koff[t]];

            v4i al0 = {0,0,0,0}, al1 = {0,0,0,0}, ah0 = {0,0,0,0}, ah1 = {0,0,0,0};
            #pragma unroll
            for (int t = 0; t < 6; t += 2) {   // 4 interleaved chains for MFMA ILP
                al0 = __builtin_amdgcn_mfma_i32_16x16x64_i8(alo[t],     bf[t],     al0, 0, 0, 0);
                ah0 = __builtin_amdgcn_mfma_i32_16x16x64_i8(ahi[t],     bf[t],     ah0, 0, 0, 0);
                al1 = __builtin_amdgcn_mfma_i32_16x16x64_i8(alo[t + 1], bf[t + 1], al1, 0, 0, 0);
                ah1 = __builtin_amdgcn_mfma_i32_16x16x64_i8(ahi[t + 1], bf[t + 1], ah1, 0, 0, 0);
            }
            al0 = __builtin_amdgcn_mfma_i32_16x16x64_i8(alo[6], bf[6], al0, 0, 0, 0);
            ah0 = __builtin_amdgcn_mfma_i32_16x16x64_i8(ahi[6], bf[6], ah0, 0, 0, 0);

            // D layout: col = lane&15 = pixel, row = g4*4 + r = channel d.
            // Lane's 4 results are d-contiguous -> one ds_write_b128.
            v4f o;
            #pragma unroll
            for (int r = 0; r < 4; ++r) {
                const int acc = (ah0[r] + ah1[r]) * 16 + (al0[r] + al1[r]);
                o[r] = fmaf((float)acc, scale, b0);
            }
            *(v4f*)(twr + (jg * 16 + m16) * TRP + g4 * 4) = o;
        }

        // Store phase: 14 fully-contiguous 256-B lines (rows 14/15 never read).
        const int i = I0 + il;
        if (i < OUT_H) {                      // wave-uniform
            const int j = J0 + lane;
            const float* tb = twr + lane * TRP;
            float* ob = out + (size_t)i * OUT_W + j;
            const bool jok = j < OUT_W;
            #pragma unroll
            for (int d = 0; d < 14; ++d) {
                if (jok) ob[(size_t)d * OUT_HW] = tb[d];
            }
        }
    }
}

extern "C" void kernel_launch(void* const* d_in, const int* in_sizes, int n_in,
                              void* d_out, int out_size, void* d_ws, size_t ws_size,
                              hipStream_t stream) {
    const int* x      = (const int*)d_in[0];
    const float* w    = (const float*)d_in[1];
    const float* bias = (const float*)d_in[2];
    float* out        = (float*)d_out;
    v4i* wfrag        = (v4i*)d_ws;   // 896 * 16B = 14336 B of workspace

    quant_frag<<<1, 64, 0, stream>>>(w, wfrag);
    conv_mfma<<<dim3((OUT_W + TJ - 1) / TJ, (OUT_H + TI - 1) / TI), 256, 0, stream>>>(
        x, wfrag, bias, out);
}

// Round 7
// 292.578 us; speedup vs baseline: 1.4807x; 1.0023x over previous
//
#include <hip/hip_runtime.h>

#define IMG_W 2048
#define IMG_H 2048
#define OUT_W 2044
#define OUT_H 2044
#define OUT_HW (2044 * 2044)

// Workgroup output tile: TI rows x TJ cols, 14 d-planes deep.
#define TI 16
#define TJ 64
#define LR (TI + 4)   // staged input rows
#define LC (TJ + 4)   // staged input cols
#define LSTR 69       // LDS row stride in 16B pixel-records
#define TRP 17        // transpose-buffer inner stride (odd -> conflict-free b32)

typedef int v4i __attribute__((ext_vector_type(4)));
typedef float v4f __attribute__((ext_vector_type(4)));

// Build MFMA A-fragments from weights.
// GEMM: D[m][n] = sum_k A[m][k]*B[k][n]; m = channel d, k = (pair p, bit-plane c),
// p = 4t + (lane>>4) over 7 chunks (25 real (kh,kw) pairs + 3 zero pads).
// 127-scale quantization: w7 = rint(w*127) in [0,127] is directly signed-i8-safe
// -> ONE A-chain (7 MFMAs/iter instead of 13). Worst-case quant error
// 75 * 0.5/127 = 0.295 < 0.5575 threshold.
__global__ void quant_frag(const float* __restrict__ w, v4i* __restrict__ wfrag) {
    const int l = threadIdx.x;
    const int m = l & 15, g = l >> 4;
    #pragma unroll
    for (int t = 0; t < 7; ++t) {
        const int p = 4 * t + g;
        unsigned b[4] = {0, 0, 0, 0};
        if (p < 25 && m < 14) {
            const int kh = p / 5, kw = p % 5;
            #pragma unroll
            for (int kd = 0; kd < 3; ++kd) {
                const int e = m + kd;                       // byte lane (bit-plane c)
                const unsigned w7 = (unsigned)(int)rintf(w[(kd * 5 + kh) * 5 + kw] * 127.0f);
                b[e >> 2] |= w7 << (8 * (e & 3));
            }
        }
        v4i va;
        va.x = (int)b[0]; va.y = (int)b[1]; va.z = (int)b[2]; va.w = (int)b[3];
        wfrag[t * 64 + l] = va;
    }
}

// Pixel-major bit-expansion in LDS (16 B/pixel = 16 bit-planes); one ds_read_b128
// per lane per k-chunk is a full B-fragment for mfma_i32_16x16x64_i8.
// Epilogue: per-wave LDS transpose so every global store is a fully-contiguous
// 256-B line (out[d][i][J0..J0+63], lane = j). Cached stores (L2 line merge).
// launch_bounds(256,4): 4 WGs/CU (LDS 39.5 KB x4 = 158 KB), 16 waves/CU to
// hide the ds_read latency that dominates this kernel.
__global__ __launch_bounds__(256, 4) void conv_mfma(
        const int* __restrict__ x, const v4i* __restrict__ wfrag,
        const float* __restrict__ bias, float* __restrict__ out) {
    __shared__ v4i vt[LR * LSTR];            // 22.1 KB
    __shared__ float trp[4 * 64 * TRP];      // 17.4 KB (per-wave 64x17 floats)
    const int tid  = threadIdx.x;
    const int lane = tid & 63;
    const int wv   = tid >> 6;     // wave 0..3
    const int m16  = lane & 15;    // pixel-in-group (B) / channel row (A)
    const int g4   = lane >> 4;    // k-subgroup / D row-block
    const int I0 = blockIdx.y * TI;
    const int J0 = blockIdx.x * TJ;

    // A-fragments: issued first so the loads overlap the staging phase below.
    v4i alo[7];
    #pragma unroll
    for (int t = 0; t < 7; ++t) alo[t] = wfrag[t * 64 + lane];
    const float b0 = bias[0];

    // ---- stage + bit-expand LR x LC pixels (load -> expand -> ds_write) ----
    #pragma unroll
    for (int rr = 0; rr < 5; ++rr) {
        const int r  = wv + rr * 4;                        // 0..19
        const int gr = min(I0 + r, IMG_H - 1);
        const long rowoff = (long)gr * IMG_W;
        #pragma unroll
        for (int cc = 0; cc < 2; ++cc) {
            const int col = lane + cc * 64;
            if (col < LC) {
                const int gc = min(J0 + col, IMG_W - 1);
                const unsigned v = (unsigned)x[rowoff + gc];
                v4i e;  // byte c of record = bit c of pixel
                e.x = (int)(__umul24( v         & 0xFu, 0x00204081u) & 0x01010101u);
                e.y = (int)(__umul24((v >> 4)   & 0xFu, 0x00204081u) & 0x01010101u);
                e.z = (int)(__umul24((v >> 8)   & 0xFu, 0x00204081u) & 0x01010101u);
                e.w = (int)(__umul24((v >> 12)  & 0xFu, 0x00204081u) & 0x01010101u);
                vt[r * LSTR + col] = e;
            }
        }
    }
    __syncthreads();

    // Per-lane k-chunk record offsets (pads -> (0,0), weights are zero there).
    int koff[7];
    #pragma unroll
    for (int t = 0; t < 7; ++t) {
        const int p  = 4 * t + g4;
        const int kh = (p < 25) ? (p / 5) : 0;
        const int kw = (p < 25) ? (p - kh * 5) : 0;
        koff[t] = kh * LSTR + kw;
    }

    const float scale = 1.0f / 127.0f;
    float* twr = trp + wv * (64 * TRP);      // this wave's private transpose buffer

    // ---- per output row (wave wv owns rows 4wv .. 4wv+3) ----
    #pragma unroll 1
    for (int il_ = 0; il_ < 4; ++il_) {
        const int il = wv * 4 + il_;

        // 4 column-groups of 16 pixels: compute and stage into trp
        #pragma unroll
        for (int jg = 0; jg < 4; ++jg) {
            const int rec = il * LSTR + jg * 16 + m16;
            v4i bf[7];
            #pragma unroll
            for (int t = 0; t < 7; ++t) bf[t] = vt[rec + koff[t]];

            v4i ac0 = {0,0,0,0}, ac1 = {0,0,0,0};
            #pragma unroll
            for (int t = 0; t < 6; t += 2) {   // 2 interleaved chains for MFMA ILP
                ac0 = __builtin_amdgcn_mfma_i32_16x16x64_i8(alo[t],     bf[t],     ac0, 0, 0, 0);
                ac1 = __builtin_amdgcn_mfma_i32_16x16x64_i8(alo[t + 1], bf[t + 1], ac1, 0, 0, 0);
            }
            ac0 = __builtin_amdgcn_mfma_i32_16x16x64_i8(alo[6], bf[6], ac0, 0, 0, 0);

            // D layout: col = lane&15 = pixel, row = g4*4 + r = channel d.
            // Lane's 4 results are d-contiguous -> one ds_write_b128.
            v4f o;
            #pragma unroll
            for (int r = 0; r < 4; ++r)
                o[r] = fmaf((float)(ac0[r] + ac1[r]), scale, b0);
            *(v4f*)(twr + (jg * 16 + m16) * TRP + g4 * 4) = o;
        }

        // Store phase: 14 fully-contiguous 256-B lines (rows 14/15 never read).
        const int i = I0 + il;
        if (i < OUT_H) {                      // wave-uniform
            const int j = J0 + lane;
            const float* tb = twr + lane * TRP;
            float* ob = out + (size_t)i * OUT_W + j;
            const bool jok = j < OUT_W;
            #pragma unroll
            for (int d = 0; d < 14; ++d) {
                if (jok) ob[(size_t)d * OUT_HW] = tb[d];
            }
        }
    }
}

extern "C" void kernel_launch(void* const* d_in, const int* in_sizes, int n_in,
                              void* d_out, int out_size, void* d_ws, size_t ws_size,
                              hipStream_t stream) {
    const int* x      = (const int*)d_in[0];
    const float* w    = (const float*)d_in[1];
    const float* bias = (const float*)d_in[2];
    float* out        = (float*)d_out;
    v4i* wfrag        = (v4i*)d_ws;   // 448 * 16B = 7168 B of workspace

    quant_frag<<<1, 64, 0, stream>>>(w, wfrag);
    conv_mfma<<<dim3((OUT_W + TJ - 1) / TJ, (OUT_H + TI - 1) / TI), 256, 0, stream>>>(
        x, wfrag, bias, out);
}

// Round 8
// 280.968 us; speedup vs baseline: 1.5419x; 1.0413x over previous
//
#include <hip/hip_runtime.h>

#define IMG_W 2048
#define IMG_H 2048
#define OUT_W 2044
#define OUT_H 2044
#define OUT_HW (2044 * 2044)

// ---- MFMA region geometry (rows 0..MROWS-1) ----
#define TI 16
#define TJ 64
#define LR (TI + 4)
#define LC (TJ + 4)
#define LSTR 69
#define TRP 17
#define MTILES_Y 56            // 56*16 = 896 rows via MFMA
#define MROWS (MTILES_Y * 16)
#define TY0 (MROWS / 2)        // dot4 ty offset (each ty = 2 rows)

typedef int v4i __attribute__((ext_vector_type(4)));
typedef float v4f __attribute__((ext_vector_type(4)));

// Combined weight prep:
//  - wfrag: MFMA A-fragments, 127-scale single-chain (R7, verified absmax 0.125)
//  - wt:    dot4 W0/W1 words, 255-scale (R0, verified absmax 0.125)
__global__ void quant_all(const float* __restrict__ w, v4i* __restrict__ wfrag,
                          unsigned* __restrict__ wt) {
    const int l = threadIdx.x;
    const int m = l & 15, g = l >> 4;
    #pragma unroll
    for (int t = 0; t < 7; ++t) {
        const int p = 4 * t + g;
        unsigned b[4] = {0, 0, 0, 0};
        if (p < 25 && m < 14) {
            const int kh = p / 5, kw = p % 5;
            #pragma unroll
            for (int kd = 0; kd < 3; ++kd) {
                const int e = m + kd;
                const unsigned w7 = (unsigned)(int)rintf(w[(kd * 5 + kh) * 5 + kw] * 127.0f);
                b[e >> 2] |= w7 << (8 * (e & 3));
            }
        }
        v4i va;
        va.x = (int)b[0]; va.y = (int)b[1]; va.z = (int)b[2]; va.w = (int)b[3];
        wfrag[t * 64 + l] = va;
    }
    if (l < 25) {
        const int kh = l / 5, kw = l % 5;
        unsigned w0 = (unsigned)(int)rintf(w[(0 * 5 + kh) * 5 + kw] * 255.0f);
        unsigned w1 = (unsigned)(int)rintf(w[(1 * 5 + kh) * 5 + kw] * 255.0f);
        unsigned w2 = (unsigned)(int)rintf(w[(2 * 5 + kh) * 5 + kw] * 255.0f);
        unsigned W0 = w0 | (w1 << 8) | (w2 << 16);
        wt[l * 2]     = W0;
        wt[l * 2 + 1] = W0 << 8;
    }
}

// ---- R0 dot4 body (proven, VALU-pipe), shifted to rows >= MROWS ----
template<int HALF>
__device__ __forceinline__ void body_dot(
        const int* __restrict__ x, const unsigned* __restrict__ wt,
        const float* __restrict__ bias, float* __restrict__ out,
        int bx, int by) {
    const int lane = threadIdx.x & 63;
    const int sub  = threadIdx.x >> 6;
    const int tx = bx * 64 + lane;
    const int ty = TY0 + by * 4 + sub;
    if (tx >= 511 || ty >= 1022) return;
    const int j0 = tx * 4;
    const int i0 = ty * 2;

    unsigned W0[5][5], W1[5][5];
    #pragma unroll
    for (int kh = 0; kh < 5; ++kh)
        #pragma unroll
        for (int kw = 0; kw < 5; ++kw) {
            W0[kh][kw] = wt[(kh * 5 + kw) * 2];
            W1[kh][kw] = wt[(kh * 5 + kw) * 2 + 1];
        }

    unsigned acc[2][4][7] = {};
    const float b0 = bias[0];

    #pragma unroll
    for (int r = 0; r < 6; ++r) {
        const int* row = x + (size_t)(i0 + r) * IMG_W + j0;
        const int4 va = *(const int4*)row;
        const int4 vb = *(const int4*)(row + 4);
        const unsigned v[8] = {(unsigned)va.x, (unsigned)va.y, (unsigned)va.z, (unsigned)va.w,
                               (unsigned)vb.x, (unsigned)vb.y, (unsigned)vb.z, (unsigned)vb.w};
        #pragma unroll
        for (int c = 0; c < 8; ++c) {
            unsigned P[4];
            #pragma unroll
            for (int u = 0; u < 4; ++u) {
                const int t = (HALF ? 3 : 0) + u;
                P[u] = __umul24((v[c] >> (2 * t)) & 0xFu, 0x00204081u) & 0x01010101u;
            }
            #pragma unroll
            for (int di = 0; di < 2; ++di) {
                const int kh = r - di;
                if (kh < 0 || kh > 4) continue;
                #pragma unroll
                for (int dj = 0; dj < 4; ++dj) {
                    const int kw = c - dj;
                    if (kw < 0 || kw > 4) continue;
                    const unsigned w0 = W0[kh][kw];
                    const unsigned w1 = W1[kh][kw];
                    if (HALF == 0) {
                        #pragma unroll
                        for (int u = 0; u < 4; ++u)
                            acc[di][dj][2 * u] = __builtin_amdgcn_udot4(P[u], w0, acc[di][dj][2 * u], false);
                        #pragma unroll
                        for (int u = 0; u < 3; ++u)
                            acc[di][dj][2 * u + 1] = __builtin_amdgcn_udot4(P[u], w1, acc[di][dj][2 * u + 1], false);
                    } else {
                        #pragma unroll
                        for (int u = 0; u < 4; ++u)
                            acc[di][dj][2 * u] = __builtin_amdgcn_udot4(P[u], w1, acc[di][dj][2 * u], false);
                        #pragma unroll
                        for (int u = 1; u < 4; ++u)
                            acc[di][dj][2 * u - 1] = __builtin_amdgcn_udot4(P[u], w0, acc[di][dj][2 * u - 1], false);
                    }
                }
            }
        }
    }

    const float scale = 1.0f / 255.0f;
    #pragma unroll
    for (int di = 0; di < 2; ++di) {
        const int i = i0 + di;
        #pragma unroll
        for (int ld = 0; ld < 7; ++ld) {
            const int d = (HALF ? 7 : 0) + ld;
            float4 o;
            o.x = fmaf((float)acc[di][0][ld], scale, b0);
            o.y = fmaf((float)acc[di][1][ld], scale, b0);
            o.z = fmaf((float)acc[di][2][ld], scale, b0);
            o.w = fmaf((float)acc[di][3][ld], scale, b0);
            *(float4*)(out + (size_t)d * OUT_HW + (size_t)i * OUT_W + j0) = o;
        }
    }
}

// ---- R7 MFMA body (proven, LDS+MFMA pipes), rows 0..MROWS-1 ----
__device__ __forceinline__ void body_mfma(
        const int* __restrict__ x, const v4i* __restrict__ wfrag,
        const float* __restrict__ bias, float* __restrict__ out,
        int I0, int J0, v4i* vt, float* trp) {
    const int tid  = threadIdx.x;
    const int lane = tid & 63;
    const int wv   = tid >> 6;
    const int m16  = lane & 15;
    const int g4   = lane >> 4;

    v4i alo[7];
    #pragma unroll
    for (int t = 0; t < 7; ++t) alo[t] = wfrag[t * 64 + lane];
    const float b0 = bias[0];

    #pragma unroll
    for (int rr = 0; rr < 5; ++rr) {
        const int r  = wv + rr * 4;
        const int gr = min(I0 + r, IMG_H - 1);
        const long rowoff = (long)gr * IMG_W;
        #pragma unroll
        for (int cc = 0; cc < 2; ++cc) {
            const int col = lane + cc * 64;
            if (col < LC) {
                const int gc = min(J0 + col, IMG_W - 1);
                const unsigned v = (unsigned)x[rowoff + gc];
                v4i e;
                e.x = (int)(__umul24( v         & 0xFu, 0x00204081u) & 0x01010101u);
                e.y = (int)(__umul24((v >> 4)   & 0xFu, 0x00204081u) & 0x01010101u);
                e.z = (int)(__umul24((v >> 8)   & 0xFu, 0x00204081u) & 0x01010101u);
                e.w = (int)(__umul24((v >> 12)  & 0xFu, 0x00204081u) & 0x01010101u);
                vt[r * LSTR + col] = e;
            }
        }
    }
    __syncthreads();

    int koff[7];
    #pragma unroll
    for (int t = 0; t < 7; ++t) {
        const int p  = 4 * t + g4;
        const int kh = (p < 25) ? (p / 5) : 0;
        const int kw = (p < 25) ? (p - kh * 5) : 0;
        koff[t] = kh * LSTR + kw;
    }

    const float scale = 1.0f / 127.0f;
    float* twr = trp + wv * (64 * TRP);

    #pragma unroll 1
    for (int il_ = 0; il_ < 4; ++il_) {
        const int il = wv * 4 + il_;

        #pragma unroll
        for (int jg = 0; jg < 4; ++jg) {
            const int rec = il * LSTR + jg * 16 + m16;
            v4i bf[7];
            #pragma unroll
            for (int t = 0; t < 7; ++t) bf[t] = vt[rec + koff[t]];

            v4i ac0 = {0,0,0,0}, ac1 = {0,0,0,0};
            #pragma unroll
            for (int t = 0; t < 6; t += 2) {
                ac0 = __builtin_amdgcn_mfma_i32_16x16x64_i8(alo[t],     bf[t],     ac0, 0, 0, 0);
                ac1 = __builtin_amdgcn_mfma_i32_16x16x64_i8(alo[t + 1], bf[t + 1], ac1, 0, 0, 0);
            }
            ac0 = __builtin_amdgcn_mfma_i32_16x16x64_i8(alo[6], bf[6], ac0, 0, 0, 0);

            v4f o;
            #pragma unroll
            for (int r = 0; r < 4; ++r)
                o[r] = fmaf((float)(ac0[r] + ac1[r]), scale, b0);
            *(v4f*)(twr + (jg * 16 + m16) * TRP + g4 * 4) = o;
        }

        const int i = I0 + il;
        if (i < OUT_H) {
            const int j = J0 + lane;
            const float* tb = twr + lane * TRP;
            float* ob = out + (size_t)i * OUT_W + j;
            const bool jok = j < OUT_W;
            #pragma unroll
            for (int d = 0; d < 14; ++d) {
                if (jok) ob[(size_t)d * OUT_HW] = tb[d];
            }
        }
    }
}

// Fused role-split kernel: period-16 interleave, 7 MFMA-blocks : 9 dot4-blocks.
// MFMA blocks cover rows 0..895 (56 y-tiles x 32 x-tiles = 1792 blocks).
// dot4 blocks cover rows 896..2043 (144 by x 8 bx x 2 halves = 2304 blocks).
// Both pipes (MFMA+LDS vs VALU) run concurrently on each CU (m114).
__global__ __launch_bounds__(256, 4) void conv_fused(
        const int* __restrict__ x, const v4i* __restrict__ wfrag,
        const unsigned* __restrict__ wt, const float* __restrict__ bias,
        float* __restrict__ out) {
    __shared__ v4i vt[LR * LSTR];
    __shared__ float trp[4 * 64 * TRP];
    const int bid = blockIdx.x;
    const int pe = bid >> 4;
    const int sl = bid & 15;
    if (sl < 7) {
        const int im = pe * 7 + sl;              // [0, 1792)
        body_mfma(x, wfrag, bias, out, (im >> 5) * 16, (im & 31) * 64, vt, trp);
    } else {
        const int id = pe * 9 + (sl - 7);        // [0, 2304)
        const int z  = id & 1;
        const int bx = (id >> 1) & 7;
        const int by = id >> 4;                  // [0, 144)
        if (z == 0) body_dot<0>(x, wt, bias, out, bx, by);
        else        body_dot<1>(x, wt, bias, out, bx, by);
    }
}

extern "C" void kernel_launch(void* const* d_in, const int* in_sizes, int n_in,
                              void* d_out, int out_size, void* d_ws, size_t ws_size,
                              hipStream_t stream) {
    const int* x      = (const int*)d_in[0];
    const float* w    = (const float*)d_in[1];
    const float* bias = (const float*)d_in[2];
    float* out        = (float*)d_out;
    v4i* wfrag        = (v4i*)d_ws;                    // 448 * 16B
    unsigned* wt      = (unsigned*)(wfrag + 448);      // 50 u32

    quant_all<<<1, 64, 0, stream>>>(w, wfrag, wt);
    conv_fused<<<dim3(4096), 256, 0, stream>>>(x, wfrag, wt, bias, out);
}